// Round 2
// baseline (670.223 us; speedup 1.0000x reference)
//
#include <hip/hip_runtime.h>
#include <hip/hip_cooperative_groups.h>
#include <stdint.h>

namespace cgx = cooperative_groups;

// PCLayer closed form, 2-launch route:
//   coop prep (1 launch, 7 phases, grid.sync between):
//     P0: WTb = bf16(W)^T [768,3072], Wb = bf16(W) [3072,768]
//     P1: E partials = lr*WT@WT^T (z=6 split-K) -> R
//     P2: Ef = sum(R); Eb = bf16(Ef)
//     P3: E^2 partials = Eb@Eb^T (z=6) -> R
//     P4: Spb = bf16(-45E + 120E^2)
//     P5: WMT = bf16(0.01*W^T + lr*S''@W^T)  [768,3072]
//     P6: c[n] = sum_k WMT[n,k]*bias[k]  (rank-1 bias correction; 0 here)
//   gemm_big: out = t @ WMT^T - c  [8192,768] fp32
// Rationale r2: (a) 7 launches -> 2 kills ~5 x ~6us dispatch overhead and the
// tb intermediate (100R+50W+50R MB gone); (b) the big GEMM was LDS-read-bound
// (83K+27K conflict cy/CU vs 18.6K MFMA cy/CU -> MfmaUtil 22.5%), so BN=256
// with 1x4 waves doubles FLOP per LDS byte (per-CU ds_read_b128 6912 -> 3456).

typedef short bf16x8 __attribute__((ext_vector_type(8)));   // 8 bf16 = 4 VGPRs
typedef float f32x4  __attribute__((ext_vector_type(4)));
typedef unsigned short u16;
typedef unsigned int uint_as1 __attribute__((address_space(1)));
typedef unsigned int uint_as3 __attribute__((address_space(3)));

__device__ __forceinline__ float bf2f(u16 u) {
  union { unsigned int i; float f; } x; x.i = ((unsigned int)u) << 16; return x.f;
}
__device__ __forceinline__ u16 f2bf(float f) {  // round-to-nearest-even
  union { float f; unsigned int i; } x; x.f = f;
  unsigned int r = x.i + 0x7fffu + ((x.i >> 16) & 1u);
  return (u16)(r >> 16);
}
__device__ __forceinline__ void gl2lds16(const void* g, void* l) {
  // async 16B/lane global->LDS; LDS dst = wave-uniform base + lane*16
  __builtin_amdgcn_global_load_lds((uint_as1*)(uintptr_t)g,
                                   (uint_as3*)(uintptr_t)l, 16, 0, 0);
}

// ---- device GEMM tile: C[M,N] = alpha * A[M,K] @ B[N,K]^T (bf16, lda=ldb=K)
// Tile TM x 128, K-chunk 32*NK per barrier (m97 LDS sub-layout per 32-slab).
// EPI 0: fp32 store at Cf + bz*zstride (split-K partials / plain)
// EPI 3: bf16 store Cb = f2bf(alpha*acc + beta*bf2f(Yb[idx]))
template<int TM, int NK, int EPI>
__device__ __forceinline__
void gemm_tile(u16* smem, const u16* __restrict__ A, const u16* __restrict__ B,
               float* __restrict__ Cf, u16* __restrict__ Cb,
               const u16* __restrict__ Yb, float alpha, float beta,
               int K, int ldc, int kc, long zstride, int bx, int by, int bz)
{
  constexpr int FM  = TM / 32;   // A frags per wave
  constexpr int RPW = TM / 4;    // A rows staged per wave
  u16* As = smem;                       // TM*32*NK
  u16* Bs = smem + TM * 32 * NK;        // 128*32*NK
  const int tid = threadIdx.x, w = tid >> 6, lane = tid & 63;
  const int lm = lane & 15, quad = lane >> 4;
  const int wm = w & 1, wn = w >> 1;
  const int m0 = bx * TM, n0 = by * 128;
  const long k0 = (long)bz * kc;
  const int r = lane >> 2, q = lane & 3;
  const u16* Ag = A + (long)(m0 + w * RPW + r) * K + k0 + q * 8;
  const u16* Bg = B + (long)(n0 + w * 32 + r) * K + k0 + q * 8;
  u16* Asl = As + w * RPW * 32;   // wave-uniform stage bases
  u16* Bsl = Bs + w * 1024;

  f32x4 acc[FM][4] = {};

  for (int kk = 0; kk < kc; kk += 32 * NK) {
#pragma unroll
    for (int h = 0; h < NK; ++h) {
#pragma unroll
      for (int l = 0; l < RPW / 16; ++l)
        gl2lds16(Ag + (long)(l * 16) * K + kk + h * 32,
                 Asl + h * TM * 32 + l * 512);
      gl2lds16(Bg + kk + h * 32, Bsl + h * 4096);
      gl2lds16(Bg + 16 * (long)K + kk + h * 32, Bsl + h * 4096 + 512);
    }
    __syncthreads();
#pragma unroll
    for (int h = 0; h < NK; ++h) {
      bf16x8 af[FM], bv[4];
#pragma unroll
      for (int i = 0; i < FM; ++i)
        af[i] = *(const bf16x8*)(As + h * TM * 32 +
                                 (wm * (TM / 2) + i * 16 + lm) * 32 + quad * 8);
#pragma unroll
      for (int j = 0; j < 4; ++j)
        bv[j] = *(const bf16x8*)(Bs + h * 4096 +
                                 (wn * 64 + j * 16 + lm) * 32 + quad * 8);
#pragma unroll
      for (int i = 0; i < FM; ++i)
#pragma unroll
        for (int j = 0; j < 4; ++j)
          acc[i][j] = __builtin_amdgcn_mfma_f32_16x16x32_bf16(af[i], bv[j],
                                                              acc[i][j], 0, 0, 0);
    }
    __syncthreads();
  }

  // C/D layout (m89-verified): col = lane&15, row = quad*4 + reg
  const int rbase = m0 + wm * (TM / 2) + quad * 4;
  const int cbase = n0 + wn * 64 + lm;
  const long zoff = (long)bz * zstride;
#pragma unroll
  for (int i = 0; i < FM; ++i)
#pragma unroll
    for (int j = 0; j < 4; ++j) {
      const int col = cbase + j * 16;
#pragma unroll
      for (int rr = 0; rr < 4; ++rr) {
        const long idx = (long)(rbase + i * 16 + rr) * ldc + col;
        const float v = alpha * acc[i][j][rr];
        if constexpr (EPI == 0) Cf[zoff + idx] = v;
        else                    Cb[idx] = f2bf(v + beta * bf2f(Yb[idx]));
      }
    }
}

// ---- cooperative prep: all of the small chain in one launch, 512x256
__global__ __launch_bounds__(256, 2)
void prep_coop(const float* __restrict__ W, const float* __restrict__ bias,
               u16* __restrict__ WTb, u16* __restrict__ Wb,
               float* __restrict__ Ef, u16* __restrict__ Eb,
               u16* __restrict__ Spb, float* __restrict__ R,
               u16* __restrict__ WMTb, float* __restrict__ cvec)
{
  __shared__ u16 smem[12288];          // 24KB: gemm As(4096)+Bs(8192); transpose 4608
  cgx::grid_group grid = cgx::this_grid();
  const int tid = threadIdx.x;
  const float lr = 0.001f;

  // P0: W transpose -> WTb [768,3072] + straight convert -> Wb [3072,768]
  for (int bt = blockIdx.x; bt < 576; bt += gridDim.x) {  // 48 x 12 tiles of 64x64
    const int o0 = (bt / 12) * 64, i0 = (bt % 12) * 64;
    const int ol = tid >> 2, cg4 = tid & 3;
#pragma unroll
    for (int p = 0; p < 4; ++p) {
      const float4 v = *(const float4*)(W + (long)(o0 + ol) * 768 + i0 + (cg4 + p * 4) * 4);
      const int ib = (cg4 + p * 4) * 4;
      smem[(ib + 0) * 72 + ol] = f2bf(v.x);
      smem[(ib + 1) * 72 + ol] = f2bf(v.y);
      smem[(ib + 2) * 72 + ol] = f2bf(v.z);
      smem[(ib + 3) * 72 + ol] = f2bf(v.w);
      ushort4 wo;
      wo.x = f2bf(v.x); wo.y = f2bf(v.y); wo.z = f2bf(v.z); wo.w = f2bf(v.w);
      ((ushort4*)(Wb + (long)(o0 + ol) * 768 + i0))[cg4 + p * 4] = wo;
    }
    __syncthreads();
    const int cl = tid >> 2, og = tid & 3;
    const u16* src = smem + cl * 72 + og * 16;
    u16* dst = WTb + (long)(i0 + cl) * 3072 + o0 + og * 16;
    ((ushort4*)dst)[0] = ((const ushort4*)src)[0];
    ((ushort4*)dst)[1] = ((const ushort4*)src)[1];
    ((ushort4*)dst)[2] = ((const ushort4*)src)[2];
    ((ushort4*)dst)[3] = ((const ushort4*)src)[3];
    __syncthreads();                   // protect LDS for next tile / next phase
  }
  grid.sync();

  // P1: E partials = lr * WT @ WT^T : K=3072, z=6, kc=512 (432 units)
  if (blockIdx.x < 432) {
    const int u = blockIdx.x;
    gemm_tile<64, 2, 0>(smem, WTb, WTb, R, nullptr, nullptr, lr, 0.f,
                        3072, 768, 512, 589824, u % 12, (u / 12) % 6, u / 72);
  }
  grid.sync();

  // P2: Ef = sum_{z<6} R[z]; Eb = bf16(Ef)   (147456 float4, grid-stride)
  for (int i4 = blockIdx.x * 256 + tid; i4 < 147456; i4 += gridDim.x * 256) {
    float4 s = make_float4(0.f, 0.f, 0.f, 0.f);
#pragma unroll
    for (int z = 0; z < 6; ++z) {
      const float4 p4 = ((const float4*)R)[(long)z * 147456 + i4];
      s.x += p4.x; s.y += p4.y; s.z += p4.z; s.w += p4.w;
    }
    ((float4*)Ef)[i4] = s;
    ushort4 o; o.x = f2bf(s.x); o.y = f2bf(s.y); o.z = f2bf(s.z); o.w = f2bf(s.w);
    ((ushort4*)Eb)[i4] = o;
  }
  grid.sync();

  // P3: E^2 partials = Eb @ Eb^T (E symmetric): K=768, z=6, kc=128
  if (blockIdx.x < 432) {
    const int u = blockIdx.x;
    gemm_tile<64, 2, 0>(smem, Eb, Eb, R, nullptr, nullptr, 1.f, 0.f,
                        768, 768, 128, 589824, u % 12, (u / 12) % 6, u / 72);
  }
  grid.sync();

  // P4: Spb = bf16(-45*Ef + 120*sum_z R[z])
  for (int i4 = blockIdx.x * 256 + tid; i4 < 147456; i4 += gridDim.x * 256) {
    float4 s = make_float4(0.f, 0.f, 0.f, 0.f);
#pragma unroll
    for (int z = 0; z < 6; ++z) {
      const float4 p4 = ((const float4*)R)[(long)z * 147456 + i4];
      s.x += p4.x; s.y += p4.y; s.z += p4.z; s.w += p4.w;
    }
    const float4 e = ((const float4*)Ef)[i4];
    ushort4 o;
    o.x = f2bf(-45.f * e.x + 120.f * s.x);
    o.y = f2bf(-45.f * e.y + 120.f * s.y);
    o.z = f2bf(-45.f * e.z + 120.f * s.z);
    o.w = f2bf(-45.f * e.w + 120.f * s.w);
    ((ushort4*)Spb)[i4] = o;
  }
  grid.sync();

  // P5: WMT = bf16(lr * S'' @ W^T + 0.01 * WT) : M=768, N=3072, K=768 (288 units)
  if (blockIdx.x < 288) {
    const int u = blockIdx.x;
    gemm_tile<64, 2, 3>(smem, Spb, Wb, nullptr, WMTb, WTb, lr, 0.01f,
                        768, 3072, 768, 0, u % 12, u / 12, 0);
  }
  grid.sync();

  // P6: c[n] = sum_k WMT[n,k] * bias[k]  (rank-1 bias fold; wave per row)
  if (blockIdx.x < 192) {
    const int w = tid >> 6, lane = tid & 63;
    const int row = blockIdx.x * 4 + w;
    float s = 0.f;
    for (int k = lane; k < 3072; k += 64)
      s += bf2f(WMTb[(long)row * 3072 + k]) * bias[k];
#pragma unroll
    for (int off = 32; off; off >>= 1) s += __shfl_down(s, off);
    if (lane == 0) cvec[row] = s;
  }
}

// ---- big GEMM: out[8192,768] = t @ WMT^T - c   (A = fp32 t, converted in-kernel)
// TM=64 x BN=256, 4 waves 1x4 (wave = 64 rows x 64 cols, FM=4): doubles FLOP
// per LDS byte vs BN=128 (LDS-read-bound fix). B via gl2lds; A reg-staged.
__global__ __launch_bounds__(256, 2)
void gemm_big(const float* __restrict__ T, const u16* __restrict__ B,
              const float* __restrict__ cvec, float* __restrict__ out)
{
  __shared__ u16 As[2 * 64 * 32];      //  8KB: [h][row64][k32]
  __shared__ u16 Bs[2 * 256 * 32];     // 32KB: [h][row256][k32]
  const int tid = threadIdx.x, w = tid >> 6, lane = tid & 63;
  const int lm = lane & 15, quad = lane >> 4;
  const int m0 = blockIdx.x * 64, n0 = blockIdx.y * 256;
  const int r = lane >> 2, q = lane & 3;
  // B staging (gl2lds): wave w stages rows n0 + w*64 + l*16 + r
  const u16* Bg = B + (long)(n0 + w * 64 + r) * 3072 + q * 8;
  u16* Bsl = Bs + w * 64 * 32;
  // A staging (fp32->bf16): thread -> rows p*16+(tid>>4), float4 at kq*4
  const int arow = tid >> 4, kq = tid & 15;
  const float* Ag = T + (long)(m0 + arow) * 3072 + kq * 4;
  const int h_a = kq >> 3, ks_a = (kq & 7) * 4;

  f32x4 acc[4][4] = {};

  for (int kk = 0; kk < 3072; kk += 64) {
#pragma unroll
    for (int h = 0; h < 2; ++h)
#pragma unroll
      for (int l = 0; l < 4; ++l)
        gl2lds16(Bg + (long)(l * 16) * 3072 + kk + h * 32,
                 Bsl + h * 8192 + l * 512);
#pragma unroll
    for (int p = 0; p < 4; ++p) {
      const float4 v = *(const float4*)(Ag + (long)(p * 16) * 3072 + kk);
      short4 o;
      o.x = (short)f2bf(v.x); o.y = (short)f2bf(v.y);
      o.z = (short)f2bf(v.z); o.w = (short)f2bf(v.w);
      *(short4*)(As + h_a * 2048 + (arow + p * 16) * 32 + ks_a) = o;
    }
    __syncthreads();
#pragma unroll
    for (int h = 0; h < 2; ++h) {
      bf16x8 af[4], bv[4];
#pragma unroll
      for (int i = 0; i < 4; ++i)
        af[i] = *(const bf16x8*)(As + h * 2048 + (i * 16 + lm) * 32 + quad * 8);
#pragma unroll
      for (int j = 0; j < 4; ++j)
        bv[j] = *(const bf16x8*)(Bs + h * 8192 + (w * 64 + j * 16 + lm) * 32 + quad * 8);
#pragma unroll
      for (int i = 0; i < 4; ++i)
#pragma unroll
        for (int j = 0; j < 4; ++j)
          acc[i][j] = __builtin_amdgcn_mfma_f32_16x16x32_bf16(af[i], bv[j],
                                                              acc[i][j], 0, 0, 0);
    }
    __syncthreads();
  }

  // C/D layout (m89-verified): col = lane&15, row = quad*4 + reg
  const int rbase = m0 + quad * 4;
  const int cbase = n0 + w * 64 + lm;
  float cj[4];
#pragma unroll
  for (int j = 0; j < 4; ++j) cj[j] = cvec[cbase + j * 16];
#pragma unroll
  for (int i = 0; i < 4; ++i)
#pragma unroll
    for (int j = 0; j < 4; ++j)
#pragma unroll
      for (int rr = 0; rr < 4; ++rr)
        out[(long)(rbase + i * 16 + rr) * 768 + cbase + j * 16] =
            acc[i][j][rr] - cj[j];
}

extern "C" void kernel_launch(void* const* d_in, const int* in_sizes, int n_in,
                              void* d_out, int out_size, void* d_ws, size_t ws_size,
                              hipStream_t stream)
{
  const float* t    = (const float*)d_in[0];   // [8,1024,3072]
  const float* W    = (const float*)d_in[1];   // [3072,768]
  const float* bias = (const float*)d_in[2];   // [3072]
  float* out = (float*)d_out;                  // [8192,768] fp32

  char* p = (char*)d_ws;                       // 33,033,216 B used
  u16*   WTb  = (u16*)(p + 0);                 //  4,718,592  bf16 W^T  [768,3072]
  u16*   Wb   = (u16*)(p + 4718592);           //  4,718,592  bf16 W    [3072,768]
  float* Ef   = (float*)(p + 9437184);         //  2,359,296  E fp32    [768,768]
  u16*   Eb   = (u16*)(p + 11796480);          //  1,179,648  bf16 E
  u16*   Spb  = (u16*)(p + 12976128);          //  1,179,648  bf16 S''
  float* R    = (float*)(p + 14155776);        // 14,155,776  partials [6][768^2]
  u16*   WMTb = (u16*)(p + 28311552);          //  4,718,592  bf16 WMT [768,3072]
  float* cvec = (float*)(p + 33030144);        //      3,072  c [768] fp32

  // Launch 1: cooperative small chain (512 blocks guaranteed co-resident:
  // 24KB LDS, launch_bounds(256,2) => 2 blocks/CU x 256 CUs)
  void* args[] = {(void*)&W, (void*)&bias, (void*)&WTb, (void*)&Wb, (void*)&Ef,
                  (void*)&Eb, (void*)&Spb, (void*)&R, (void*)&WMTb, (void*)&cvec};
  hipLaunchCooperativeKernel((void*)prep_coop, dim3(512), dim3(256), args, 0, stream);

  // Launch 2: out = t @ WMT^T - c : grid 128x3 = 384 blocks (TM=64, BN=256)
  gemm_big<<<dim3(128, 3), 256, 0, stream>>>(t, WMTb, cvec, out);
}

// Round 3
// 290.470 us; speedup vs baseline: 2.3074x; 2.3074x over previous
//
#include <hip/hip_runtime.h>
#include <stdint.h>

// PCLayer closed form, 5-launch route (r3):
//   conv_w : WTb = bf16(W)^T [768,3072], Wb = bf16(W) [3072,768], cvec = 0
//   E      : Ef(fp32)+Eb(bf16) = lr * WTb @ WTb^T   (one-shot, EPI 5)
//   S''    : Spb = bf16(120*(Eb@Eb^T) - 45*Ef)      (one-shot, EPI 4)
//   WMT    : WMTb = bf16(lr*Spb@Wb^T + 0.01*WTb); cvec += WMT@bias (EPI 3)
//   big    : out = t @ WMT^T - cvec  [8192,768] fp32
// r3 changes vs r1/r2: cooperative grid.sync reverted (r2: 6 syncs = ~420us,
// MfmaUtil 0.7%). Small chain collapsed 6 kernels -> 4 via fused epilogues
// (split-K + red_e + red_s deleted; all small GEMMs latency-bound anyway).
// gemm_big: BN=256 (2048 FLOP/LDS-byte vs 1365), fp32-t direct (tb gone),
// and T2 XOR chunk-swizzle: r1 big GEMM had 7.08M bank-conflict cycles
// (64B LDS rows -> quarter-wave hits banks {0,16} = 8-way). A side swizzled
// write+read; B side pre-swizzled global source + swizzled read (rule #21).

typedef short bf16x8 __attribute__((ext_vector_type(8)));   // 8 bf16 = 4 VGPRs
typedef float f32x4  __attribute__((ext_vector_type(4)));
typedef unsigned short u16;
typedef unsigned int uint_as1 __attribute__((address_space(1)));
typedef unsigned int uint_as3 __attribute__((address_space(3)));

__device__ __forceinline__ float bf2f(u16 u) {
  union { unsigned int i; float f; } x; x.i = ((unsigned int)u) << 16; return x.f;
}
__device__ __forceinline__ u16 f2bf(float f) {  // round-to-nearest-even
  union { float f; unsigned int i; } x; x.f = f;
  unsigned int r = x.i + 0x7fffu + ((x.i >> 16) & 1u);
  return (u16)(r >> 16);
}
__device__ __forceinline__ void gl2lds16(const void* g, void* l) {
  // async 16B/lane global->LDS; LDS dst = wave-uniform base + lane*16
  __builtin_amdgcn_global_load_lds((uint_as1*)(uintptr_t)g,
                                   (uint_as3*)(uintptr_t)l, 16, 0, 0);
}

// ---- small GEMM: C[M,N] = alpha * A[M,K] @ B[N,K]^T (bf16, lda=ldb=K),
// one-shot over K. Tile 64 x 128, 4 waves 2x2. Latency-bound (<=288 blocks);
// unswizzled LDS (proven path, not the bottleneck).
// EPI 3: Cb = f2bf(alpha*acc + beta*bf2f(Yb[idx])); cvec[row] += Cb_val*bias[col]
// EPI 4: Cb = f2bf(alpha*acc + beta*Cf[idx])        (Cf read-only fp32)
// EPI 5: Cf = alpha*acc (fp32)  AND  Cb = f2bf(same)
template<int NK, int EPI>
__global__ __launch_bounds__(256, 2)
void gemm_lds(const u16* __restrict__ A, const u16* __restrict__ B,
              float* __restrict__ Cf, u16* __restrict__ Cb,
              const u16* __restrict__ Yb, const float* __restrict__ biasp,
              float* __restrict__ cvec, float alpha, float beta, int K, int ldc)
{
  __shared__ u16 As[64 * 32 * NK];
  __shared__ u16 Bs[128 * 32 * NK];
  const int tid = threadIdx.x, w = tid >> 6, lane = tid & 63;
  const int lm = lane & 15, quad = lane >> 4;
  const int wm = w & 1, wn = w >> 1;
  const int m0 = blockIdx.x * 64, n0 = blockIdx.y * 128;
  const int r = lane >> 2, q = lane & 3;
  const u16* Ag = A + (long)(m0 + w * 16 + r) * K + q * 8;
  const u16* Bg = B + (long)(n0 + w * 32 + r) * K + q * 8;
  u16* Asl = As + w * 16 * 32;   // wave-uniform stage bases
  u16* Bsl = Bs + w * 1024;

  f32x4 acc[2][4] = {};

  for (int kk = 0; kk < K; kk += 32 * NK) {
#pragma unroll
    for (int h = 0; h < NK; ++h) {
      gl2lds16(Ag + kk + h * 32, Asl + h * 2048);
      gl2lds16(Bg + kk + h * 32, Bsl + h * 4096);
      gl2lds16(Bg + 16 * (long)K + kk + h * 32, Bsl + h * 4096 + 512);
    }
    __syncthreads();
#pragma unroll
    for (int h = 0; h < NK; ++h) {
      bf16x8 af[2], bv[4];
#pragma unroll
      for (int i = 0; i < 2; ++i)
        af[i] = *(const bf16x8*)(As + h * 2048 +
                                 (wm * 32 + i * 16 + lm) * 32 + quad * 8);
#pragma unroll
      for (int j = 0; j < 4; ++j)
        bv[j] = *(const bf16x8*)(Bs + h * 4096 +
                                 (wn * 64 + j * 16 + lm) * 32 + quad * 8);
#pragma unroll
      for (int i = 0; i < 2; ++i)
#pragma unroll
        for (int j = 0; j < 4; ++j)
          acc[i][j] = __builtin_amdgcn_mfma_f32_16x16x32_bf16(af[i], bv[j],
                                                              acc[i][j], 0, 0, 0);
    }
    __syncthreads();
  }

  // C/D layout (m89-verified): col = lane&15, row = quad*4 + reg
  const int rbase = m0 + wm * 32 + quad * 4;
  const int cbase = n0 + wn * 64 + lm;
  float bvals[4] = {};
  bool haveb = false;
  if constexpr (EPI == 3) {
#pragma unroll
    for (int j = 0; j < 4; ++j) bvals[j] = biasp[cbase + j * 16];
    haveb = (bvals[0] != 0.f) | (bvals[1] != 0.f) |
            (bvals[2] != 0.f) | (bvals[3] != 0.f);
  }
  float rowsum[2][4] = {};
#pragma unroll
  for (int i = 0; i < 2; ++i)
#pragma unroll
    for (int j = 0; j < 4; ++j) {
      const int col = cbase + j * 16;
#pragma unroll
      for (int rr = 0; rr < 4; ++rr) {
        const long idx = (long)(rbase + i * 16 + rr) * ldc + col;
        const float v = alpha * acc[i][j][rr];
        if constexpr (EPI == 3) {
          const u16 qv = f2bf(v + beta * bf2f(Yb[idx]));
          Cb[idx] = qv;
          rowsum[i][rr] += bf2f(qv) * bvals[j];
        } else if constexpr (EPI == 4) {
          Cb[idx] = f2bf(v + beta * Cf[idx]);
        } else {  // EPI 5
          Cf[idx] = v;
          Cb[idx] = f2bf(v);
        }
      }
    }
  if constexpr (EPI == 3) {
    if (__any(haveb)) {          // bias == 0 here -> whole fold skipped
#pragma unroll
      for (int i = 0; i < 2; ++i)
#pragma unroll
        for (int rr = 0; rr < 4; ++rr) {
          float s = rowsum[i][rr];
          s += __shfl_xor(s, 1); s += __shfl_xor(s, 2);
          s += __shfl_xor(s, 4); s += __shfl_xor(s, 8);
          if (lm == 0) atomicAdd(&cvec[rbase + i * 16 + rr], s);
        }
    }
  }
}

// ---- conv_w: WTb = bf16(W)^T via LDS-tiled transpose (48x12 tiles of 64x64),
// Wb = bf16(W) straight, cvec zeroed by block 0.
__global__ void conv_w(const float* __restrict__ W, u16* __restrict__ WTb,
                       u16* __restrict__ Wb, float* __restrict__ cvec)
{
  __shared__ u16 lds[64 * 72];              // [i_local][o_local], stride 72
  const int bt = blockIdx.x, tid = threadIdx.x;
  if (bt == 0) { cvec[tid] = 0.f; cvec[tid + 256] = 0.f; cvec[tid + 512] = 0.f; }
  const int o0 = (bt / 12) * 64, i0 = (bt % 12) * 64;
  const int ol = tid >> 2, cg4 = tid & 3;   // 64 o-rows, 4 col-groups
#pragma unroll
  for (int p = 0; p < 4; ++p) {             // 16 float4 per o-row
    const float4 v = *(const float4*)(W + (long)(o0 + ol) * 768 + i0 + (cg4 + p * 4) * 4);
    const int ib = (cg4 + p * 4) * 4;
    lds[(ib + 0) * 72 + ol] = f2bf(v.x);
    lds[(ib + 1) * 72 + ol] = f2bf(v.y);
    lds[(ib + 2) * 72 + ol] = f2bf(v.z);
    lds[(ib + 3) * 72 + ol] = f2bf(v.w);
    ushort4 wo;
    wo.x = f2bf(v.x); wo.y = f2bf(v.y); wo.z = f2bf(v.z); wo.w = f2bf(v.w);
    ((ushort4*)(Wb + (long)(o0 + ol) * 768 + i0))[cg4 + p * 4] = wo;
  }
  __syncthreads();
  const int cl = tid >> 2, og = tid & 3;    // 64 i-rows, 4 o-groups of 16
  const u16* src = lds + cl * 72 + og * 16;
  u16* dst = WTb + (long)(i0 + cl) * 3072 + o0 + og * 16;
  ((ushort4*)dst)[0] = ((const ushort4*)src)[0];
  ((ushort4*)dst)[1] = ((const ushort4*)src)[1];
  ((ushort4*)dst)[2] = ((const ushort4*)src)[2];
  ((ushort4*)dst)[3] = ((const ushort4*)src)[3];
}

// ---- big GEMM: out[8192,768] = t @ WMT^T - cvec  (A = fp32 t, cvt in-kernel)
// TM=64 x BN=256, 4 waves 1x4 (wave = 64x64, FM=4). T2 XOR chunk-swizzle:
// slot' = slot ^ ((row>>2)&3) within each 64B LDS row -> fragment reads go
// from 8-way bank conflict (banks {0,16} only) to 2 lanes/bank (free, m136).
// A: swizzle applied on ds_write AND read. B: gl2lds dest stays linear, the
// GLOBAL source chunk is pre-swizzled per-lane; read applies same XOR.
__global__ __launch_bounds__(256, 2)
void gemm_big(const float* __restrict__ T, const u16* __restrict__ B,
              const float* __restrict__ cvec, float* __restrict__ out)
{
  __shared__ u16 As[2 * 64 * 32];      //  8KB: [h][row64][k32]
  __shared__ u16 Bs[2 * 256 * 32];     // 32KB: [h][row256][k32]
  const int tid = threadIdx.x, w = tid >> 6, lane = tid & 63;
  const int lm = lane & 15, quad = lane >> 4;
  const int m0 = blockIdx.x * 64, n0 = blockIdx.y * 256;
  const int r = lane >> 2, q = lane & 3;
  const int qs = q ^ ((r >> 2) & 3);   // B global-source chunk swizzle
  const u16* Bg = B + (long)(n0 + w * 64 + r) * 3072 + qs * 8;
  u16* Bsl = Bs + w * 64 * 32;
  // A staging (fp32->bf16): thread -> rows arow+p*16, float4 at kq*4
  const int arow = tid >> 4, kq = tid & 15;
  const float* Ag = T + (long)(m0 + arow) * 3072 + kq * 4;
  const int h_a = kq >> 3;
  const int chunk_a = ((kq & 7) >> 1) ^ ((arow >> 2) & 3);   // write swizzle
  const int ks_a = chunk_a * 8 + (kq & 1) * 4;               // u16 units
  const int swr = (lm >> 2) & 3;       // reader swizzle key

  f32x4 acc[4][4] = {};

  for (int kk = 0; kk < 3072; kk += 64) {
#pragma unroll
    for (int h = 0; h < 2; ++h)
#pragma unroll
      for (int l = 0; l < 4; ++l)
        gl2lds16(Bg + (long)(l * 16) * 3072 + kk + h * 32,
                 Bsl + h * 8192 + l * 512);
#pragma unroll
    for (int p = 0; p < 4; ++p) {
      const float4 v = *(const float4*)(Ag + (long)(p * 16) * 3072 + kk);
      short4 o;
      o.x = (short)f2bf(v.x); o.y = (short)f2bf(v.y);
      o.z = (short)f2bf(v.z); o.w = (short)f2bf(v.w);
      *(short4*)(As + h_a * 2048 + (arow + p * 16) * 32 + ks_a) = o;
    }
    __syncthreads();
#pragma unroll
    for (int h = 0; h < 2; ++h) {
      bf16x8 af[4], bv[4];
#pragma unroll
      for (int i = 0; i < 4; ++i)
        af[i] = *(const bf16x8*)(As + h * 2048 + (i * 16 + lm) * 32 +
                                 ((quad ^ swr) * 8));
#pragma unroll
      for (int j = 0; j < 4; ++j)
        bv[j] = *(const bf16x8*)(Bs + h * 8192 + (w * 64 + j * 16 + lm) * 32 +
                                 ((quad ^ swr) * 8));
#pragma unroll
      for (int i = 0; i < 4; ++i)
#pragma unroll
        for (int j = 0; j < 4; ++j)
          acc[i][j] = __builtin_amdgcn_mfma_f32_16x16x32_bf16(af[i], bv[j],
                                                              acc[i][j], 0, 0, 0);
    }
    __syncthreads();
  }

  // C/D layout (m89-verified): col = lane&15, row = quad*4 + reg
  const int rbase = m0 + quad * 4;
  const int cbase = n0 + w * 64 + lm;
  float cj[4];
#pragma unroll
  for (int j = 0; j < 4; ++j) cj[j] = cvec[cbase + j * 16];
#pragma unroll
  for (int i = 0; i < 4; ++i)
#pragma unroll
    for (int j = 0; j < 4; ++j)
#pragma unroll
      for (int rr = 0; rr < 4; ++rr)
        out[(long)(rbase + i * 16 + rr) * 768 + cbase + j * 16] =
            acc[i][j][rr] - cj[j];
}

extern "C" void kernel_launch(void* const* d_in, const int* in_sizes, int n_in,
                              void* d_out, int out_size, void* d_ws, size_t ws_size,
                              hipStream_t stream)
{
  const float* t    = (const float*)d_in[0];   // [8,1024,3072]
  const float* W    = (const float*)d_in[1];   // [3072,768]
  const float* bias = (const float*)d_in[2];   // [3072]
  float* out = (float*)d_out;                  // [8192,768] fp32

  char* p = (char*)d_ws;                       // 18,877,440 B used
  u16*   WTb  = (u16*)(p + 0);                 //  4,718,592  bf16 W^T  [768,3072]
  u16*   Wb   = (u16*)(p + 4718592);           //  4,718,592  bf16 W    [3072,768]
  float* Ef   = (float*)(p + 9437184);         //  2,359,296  E fp32    [768,768]
  u16*   Eb   = (u16*)(p + 11796480);          //  1,179,648  bf16 E
  u16*   Spb  = (u16*)(p + 12976128);          //  1,179,648  bf16 S''
  u16*   WMTb = (u16*)(p + 14155776);          //  4,718,592  bf16 WMT [768,3072]
  float* cvec = (float*)(p + 18874368);        //      3,072  c [768] fp32

  const float lr = 0.001f;

  // 1. WTb + Wb + cvec=0  (576 blocks)
  conv_w<<<576, 256, 0, stream>>>(W, WTb, Wb, cvec);
  // 2. Ef,Eb = lr * WT @ WT^T : one-shot K=3072 (72 blocks, 48 iters)
  gemm_lds<2, 5><<<dim3(12, 6), 256, 0, stream>>>(
      WTb, WTb, Ef, Eb, nullptr, nullptr, nullptr, lr, 0.f, 3072, 768);
  // 3. Spb = bf16(120*(Eb@Eb^T) - 45*Ef) : K=768 (72 blocks, 12 iters)
  gemm_lds<2, 4><<<dim3(12, 6), 256, 0, stream>>>(
      Eb, Eb, Ef, Spb, nullptr, nullptr, nullptr, 120.f, -45.f, 768, 768);
  // 4. WMTb = bf16(lr*Spb@Wb^T + 0.01*WTb); cvec += WMT@bias (288 blocks)
  gemm_lds<2, 3><<<dim3(12, 24), 256, 0, stream>>>(
      Spb, Wb, nullptr, WMTb, WTb, bias, cvec, lr, 0.01f, 768, 3072);
  // 5. out = t @ WMT^T - cvec : grid 128x3 = 384 blocks (TM=64, BN=256)
  gemm_big<<<dim3(128, 3), 256, 0, stream>>>(t, WMTb, cvec, out);
}

// Round 4
// 281.391 us; speedup vs baseline: 2.3818x; 1.0323x over previous
//
#include <hip/hip_runtime.h>
#include <stdint.h>

// PCLayer closed form, 5-launch route (r4):
//   conv_w : WTb = bf16(W)^T [768,3072], Wb = bf16(W) [3072,768], cvec = 0
//   E      : Ef(fp32)+Eb(bf16) = lr * WTb @ WTb^T   (one-shot, EPI 5)
//   S''    : Spb = bf16(120*(Eb@Eb^T) - 45*Ef)      (one-shot, EPI 4)
//   WMT    : WMTb = bf16(lr*Spb@Wb^T + 0.01*WTb); cvec += WMT@bias (EPI 3)
//   big    : out = t @ WMT^T - cvec  [8192,768] fp32
// r4 vs r3:
//  - ALL swizzles removed: R1/R3 counters show SQ_LDS_BANK_CONFLICT == exactly
//    4 cy per ds_read_b128 (inherent b128 overhead, m134), not a layout issue.
//  - gemm_big keeps fp32-t direct (saves 100MB + conv pass) but staging is now
//    ASYNC (T14): barrier -> issue B(k+1) gl2lds into DOUBLE-BUFFERED Bs +
//    A(k+1) fp32 loads to regs -> MFMA(k) covers the latency -> barrier
//    (drains landed loads, cheap) -> cvt+ds_write A(k+1). R3's 104us came from
//    synchronous load->cvt->write on the critical path at 1.5 blocks/CU.
//  - small GEMMs NK=2 -> NK=4 (BK=128): halves serial iter count (E 48->24)
//    for these latency-chain kernels (72-288 blocks).

typedef short bf16x8 __attribute__((ext_vector_type(8)));   // 8 bf16 = 4 VGPRs
typedef float f32x4  __attribute__((ext_vector_type(4)));
typedef unsigned short u16;
typedef unsigned int uint_as1 __attribute__((address_space(1)));
typedef unsigned int uint_as3 __attribute__((address_space(3)));

__device__ __forceinline__ float bf2f(u16 u) {
  union { unsigned int i; float f; } x; x.i = ((unsigned int)u) << 16; return x.f;
}
__device__ __forceinline__ u16 f2bf(float f) {  // round-to-nearest-even
  union { float f; unsigned int i; } x; x.f = f;
  unsigned int r = x.i + 0x7fffu + ((x.i >> 16) & 1u);
  return (u16)(r >> 16);
}
__device__ __forceinline__ void gl2lds16(const void* g, void* l) {
  // async 16B/lane global->LDS; LDS dst = wave-uniform base + lane*16
  __builtin_amdgcn_global_load_lds((uint_as1*)(uintptr_t)g,
                                   (uint_as3*)(uintptr_t)l, 16, 0, 0);
}

// ---- small GEMM: C[M,N] = alpha * A[M,K] @ B[N,K]^T (bf16, lda=ldb=K),
// one-shot over K. Tile 64 x 128, 4 waves 2x2, BK = 32*NK.
// EPI 3: Cb = f2bf(alpha*acc + beta*bf2f(Yb[idx])); cvec[row] += Cb_val*bias[col]
// EPI 4: Cb = f2bf(alpha*acc + beta*Cf[idx])        (Cf read-only fp32)
// EPI 5: Cf = alpha*acc (fp32)  AND  Cb = f2bf(same)
template<int NK, int EPI>
__global__ __launch_bounds__(256, 2)
void gemm_lds(const u16* __restrict__ A, const u16* __restrict__ B,
              float* __restrict__ Cf, u16* __restrict__ Cb,
              const u16* __restrict__ Yb, const float* __restrict__ biasp,
              float* __restrict__ cvec, float alpha, float beta, int K, int ldc)
{
  __shared__ u16 As[64 * 32 * NK];
  __shared__ u16 Bs[128 * 32 * NK];
  const int tid = threadIdx.x, w = tid >> 6, lane = tid & 63;
  const int lm = lane & 15, quad = lane >> 4;
  const int wm = w & 1, wn = w >> 1;
  const int m0 = blockIdx.x * 64, n0 = blockIdx.y * 128;
  const int r = lane >> 2, q = lane & 3;
  const u16* Ag = A + (long)(m0 + w * 16 + r) * K + q * 8;
  const u16* Bg = B + (long)(n0 + w * 32 + r) * K + q * 8;
  u16* Asl = As + w * 16 * 32;   // wave-uniform stage bases
  u16* Bsl = Bs + w * 1024;

  f32x4 acc[2][4] = {};

  for (int kk = 0; kk < K; kk += 32 * NK) {
#pragma unroll
    for (int h = 0; h < NK; ++h) {
      gl2lds16(Ag + kk + h * 32, Asl + h * 2048);
      gl2lds16(Bg + kk + h * 32, Bsl + h * 4096);
      gl2lds16(Bg + 16 * (long)K + kk + h * 32, Bsl + h * 4096 + 512);
    }
    __syncthreads();
#pragma unroll
    for (int h = 0; h < NK; ++h) {
      bf16x8 af[2], bv[4];
#pragma unroll
      for (int i = 0; i < 2; ++i)
        af[i] = *(const bf16x8*)(As + h * 2048 +
                                 (wm * 32 + i * 16 + lm) * 32 + quad * 8);
#pragma unroll
      for (int j = 0; j < 4; ++j)
        bv[j] = *(const bf16x8*)(Bs + h * 4096 +
                                 (wn * 64 + j * 16 + lm) * 32 + quad * 8);
#pragma unroll
      for (int i = 0; i < 2; ++i)
#pragma unroll
        for (int j = 0; j < 4; ++j)
          acc[i][j] = __builtin_amdgcn_mfma_f32_16x16x32_bf16(af[i], bv[j],
                                                              acc[i][j], 0, 0, 0);
    }
    __syncthreads();
  }

  // C/D layout (m89-verified): col = lane&15, row = quad*4 + reg
  const int rbase = m0 + wm * 32 + quad * 4;
  const int cbase = n0 + wn * 64 + lm;
  float bvals[4] = {};
  bool haveb = false;
  if constexpr (EPI == 3) {
#pragma unroll
    for (int j = 0; j < 4; ++j) bvals[j] = biasp[cbase + j * 16];
    haveb = (bvals[0] != 0.f) | (bvals[1] != 0.f) |
            (bvals[2] != 0.f) | (bvals[3] != 0.f);
  }
  float rowsum[2][4] = {};
#pragma unroll
  for (int i = 0; i < 2; ++i)
#pragma unroll
    for (int j = 0; j < 4; ++j) {
      const int col = cbase + j * 16;
#pragma unroll
      for (int rr = 0; rr < 4; ++rr) {
        const long idx = (long)(rbase + i * 16 + rr) * ldc + col;
        const float v = alpha * acc[i][j][rr];
        if constexpr (EPI == 3) {
          const u16 qv = f2bf(v + beta * bf2f(Yb[idx]));
          Cb[idx] = qv;
          rowsum[i][rr] += bf2f(qv) * bvals[j];
        } else if constexpr (EPI == 4) {
          Cb[idx] = f2bf(v + beta * Cf[idx]);
        } else {  // EPI 5
          Cf[idx] = v;
          Cb[idx] = f2bf(v);
        }
      }
    }
  if constexpr (EPI == 3) {
    if (__any(haveb)) {          // bias == 0 here -> whole fold skipped
#pragma unroll
      for (int i = 0; i < 2; ++i)
#pragma unroll
        for (int rr = 0; rr < 4; ++rr) {
          float s = rowsum[i][rr];
          s += __shfl_xor(s, 1); s += __shfl_xor(s, 2);
          s += __shfl_xor(s, 4); s += __shfl_xor(s, 8);
          if (lm == 0) atomicAdd(&cvec[rbase + i * 16 + rr], s);
        }
    }
  }
}

// ---- conv_w: WTb = bf16(W)^T via LDS-tiled transpose (48x12 tiles of 64x64),
// Wb = bf16(W) straight, cvec zeroed by block 0.
__global__ void conv_w(const float* __restrict__ W, u16* __restrict__ WTb,
                       u16* __restrict__ Wb, float* __restrict__ cvec)
{
  __shared__ u16 lds[64 * 72];              // [i_local][o_local], stride 72
  const int bt = blockIdx.x, tid = threadIdx.x;
  if (bt == 0) { cvec[tid] = 0.f; cvec[tid + 256] = 0.f; cvec[tid + 512] = 0.f; }
  const int o0 = (bt / 12) * 64, i0 = (bt % 12) * 64;
  const int ol = tid >> 2, cg4 = tid & 3;   // 64 o-rows, 4 col-groups
#pragma unroll
  for (int p = 0; p < 4; ++p) {             // 16 float4 per o-row
    const float4 v = *(const float4*)(W + (long)(o0 + ol) * 768 + i0 + (cg4 + p * 4) * 4);
    const int ib = (cg4 + p * 4) * 4;
    lds[(ib + 0) * 72 + ol] = f2bf(v.x);
    lds[(ib + 1) * 72 + ol] = f2bf(v.y);
    lds[(ib + 2) * 72 + ol] = f2bf(v.z);
    lds[(ib + 3) * 72 + ol] = f2bf(v.w);
    ushort4 wo;
    wo.x = f2bf(v.x); wo.y = f2bf(v.y); wo.z = f2bf(v.z); wo.w = f2bf(v.w);
    ((ushort4*)(Wb + (long)(o0 + ol) * 768 + i0))[cg4 + p * 4] = wo;
  }
  __syncthreads();
  const int cl = tid >> 2, og = tid & 3;    // 64 i-rows, 4 o-groups of 16
  const u16* src = lds + cl * 72 + og * 16;
  u16* dst = WTb + (long)(i0 + cl) * 3072 + o0 + og * 16;
  ((ushort4*)dst)[0] = ((const ushort4*)src)[0];
  ((ushort4*)dst)[1] = ((const ushort4*)src)[1];
  ((ushort4*)dst)[2] = ((const ushort4*)src)[2];
  ((ushort4*)dst)[3] = ((const ushort4*)src)[3];
}

// ---- big GEMM: out[8192,768] = t @ WMT^T - cvec  (A = fp32 t, cvt in-kernel)
// TM=64 x BN=256, 4 waves 1x4 (wave = 64x64, FM=4). ASYNC staging (T14):
//   top barrier (tiles k ready) -> issue B(k+1) gl2lds into Bs[buf^1] +
//   A(k+1) fp32 loads to regs -> MFMA on tiles(k) (~700cy, hides latency) ->
//   barrier (drains landed prefetch + As reads done) -> cvt+ds_write A(k+1).
// Bs double-buffered (2x32KB) so B prefetch has a free destination.
// LDS 72KB -> 2 blocks/CU cap; grid 384. No swizzles (conflicts proven to be
// the inherent 4cy/ds_read_b128 overhead, not layout).
__global__ __launch_bounds__(256, 2)
void gemm_big(const float* __restrict__ T, const u16* __restrict__ B,
              const float* __restrict__ cvec, float* __restrict__ out)
{
  __shared__ u16 As[2 * 64 * 32];          //  8KB: [h][row64][k32]
  __shared__ u16 Bs[2][2 * 256 * 32];      // 2 x 32KB: [buf][h][row256][k32]
  const int tid = threadIdx.x, w = tid >> 6, lane = tid & 63;
  const int lm = lane & 15, quad = lane >> 4;
  const int m0 = blockIdx.x * 64, n0 = blockIdx.y * 256;
  const int r = lane >> 2, q = lane & 3;
  const u16* Bg = B + (long)(n0 + w * 64 + r) * 3072 + q * 8;
  // A: thread -> rows arow + p*16, float4 chunk kq
  const int arow = tid >> 4, kq = tid & 15;
  const float* Ag = T + (long)(m0 + arow) * 3072 + kq * 4;
  const int h_a = kq >> 3, ks_a = (kq & 7) * 4;
  u16* As_dst = As + h_a * 2048 + arow * 32 + ks_a;   // +p*512 per row-block

  f32x4 acc[4][4] = {};
  float4 av[4];

  // prologue: A(0) -> regs -> LDS;  B(0) -> Bs[0]
#pragma unroll
  for (int p = 0; p < 4; ++p)
    av[p] = *(const float4*)(Ag + (long)(p * 16) * 3072);
#pragma unroll
  for (int h = 0; h < 2; ++h)
#pragma unroll
    for (int l = 0; l < 4; ++l)
      gl2lds16(Bg + (long)(l * 16) * 3072 + h * 32,
               Bs[0] + h * 8192 + w * 2048 + l * 512);
#pragma unroll
  for (int p = 0; p < 4; ++p) {
    short4 o;
    o.x = (short)f2bf(av[p].x); o.y = (short)f2bf(av[p].y);
    o.z = (short)f2bf(av[p].z); o.w = (short)f2bf(av[p].w);
    *(short4*)(As_dst + p * 512) = o;
  }

  int buf = 0;
  for (int kk = 0; kk < 3072; kk += 64) {
    __syncthreads();                       // tiles(kk) ready (A lgkm, B vm)
    const bool haveNext = (kk + 64 < 3072);
    if (haveNext) {
      // prefetch issue — lands during the MFMA cluster below
#pragma unroll
      for (int h = 0; h < 2; ++h)
#pragma unroll
        for (int l = 0; l < 4; ++l)
          gl2lds16(Bg + (long)(l * 16) * 3072 + kk + 64 + h * 32,
                   Bs[buf ^ 1] + h * 8192 + w * 2048 + l * 512);
#pragma unroll
      for (int p = 0; p < 4; ++p)
        av[p] = *(const float4*)(Ag + (long)(p * 16) * 3072 + kk + 64);
    }
    const u16* Bsb = Bs[buf];
#pragma unroll
    for (int h = 0; h < 2; ++h) {
      bf16x8 af[4], bv[4];
#pragma unroll
      for (int i = 0; i < 4; ++i)
        af[i] = *(const bf16x8*)(As + h * 2048 + (i * 16 + lm) * 32 + quad * 8);
#pragma unroll
      for (int j = 0; j < 4; ++j)
        bv[j] = *(const bf16x8*)(Bsb + h * 8192 + (w * 64 + j * 16 + lm) * 32 + quad * 8);
#pragma unroll
      for (int i = 0; i < 4; ++i)
#pragma unroll
        for (int j = 0; j < 4; ++j)
          acc[i][j] = __builtin_amdgcn_mfma_f32_16x16x32_bf16(af[i], bv[j],
                                                              acc[i][j], 0, 0, 0);
    }
    if (haveNext) {
      __syncthreads();                     // As(kk) reads done; prefetch landed
#pragma unroll
      for (int p = 0; p < 4; ++p) {
        short4 o;
        o.x = (short)f2bf(av[p].x); o.y = (short)f2bf(av[p].y);
        o.z = (short)f2bf(av[p].z); o.w = (short)f2bf(av[p].w);
        *(short4*)(As_dst + p * 512) = o;
      }
      buf ^= 1;
    }
  }

  // C/D layout (m89-verified): col = lane&15, row = quad*4 + reg
  const int rbase = m0 + quad * 4;
  const int cbase = n0 + w * 64 + lm;
  float cj[4];
#pragma unroll
  for (int j = 0; j < 4; ++j) cj[j] = cvec[cbase + j * 16];
#pragma unroll
  for (int i = 0; i < 4; ++i)
#pragma unroll
    for (int j = 0; j < 4; ++j)
#pragma unroll
      for (int rr = 0; rr < 4; ++rr)
        out[(long)(rbase + i * 16 + rr) * 768 + cbase + j * 16] =
            acc[i][j][rr] - cj[j];
}

extern "C" void kernel_launch(void* const* d_in, const int* in_sizes, int n_in,
                              void* d_out, int out_size, void* d_ws, size_t ws_size,
                              hipStream_t stream)
{
  const float* t    = (const float*)d_in[0];   // [8,1024,3072]
  const float* W    = (const float*)d_in[1];   // [3072,768]
  const float* bias = (const float*)d_in[2];   // [3072]
  float* out = (float*)d_out;                  // [8192,768] fp32

  char* p = (char*)d_ws;                       // 18,877,440 B used
  u16*   WTb  = (u16*)(p + 0);                 //  4,718,592  bf16 W^T  [768,3072]
  u16*   Wb   = (u16*)(p + 4718592);           //  4,718,592  bf16 W    [3072,768]
  float* Ef   = (float*)(p + 9437184);         //  2,359,296  E fp32    [768,768]
  u16*   Eb   = (u16*)(p + 11796480);          //  1,179,648  bf16 E
  u16*   Spb  = (u16*)(p + 12976128);          //  1,179,648  bf16 S''
  u16*   WMTb = (u16*)(p + 14155776);          //  4,718,592  bf16 WMT [768,3072]
  float* cvec = (float*)(p + 18874368);        //      3,072  c [768] fp32

  const float lr = 0.001f;

  // 1. WTb + Wb + cvec=0  (576 blocks)
  conv_w<<<576, 256, 0, stream>>>(W, WTb, Wb, cvec);
  // 2. Ef,Eb = lr * WT @ WT^T : one-shot K=3072, BK=128 (72 blocks, 24 iters)
  gemm_lds<4, 5><<<dim3(12, 6), 256, 0, stream>>>(
      WTb, WTb, Ef, Eb, nullptr, nullptr, nullptr, lr, 0.f, 3072, 768);
  // 3. Spb = bf16(120*(Eb@Eb^T) - 45*Ef) : K=768, BK=128 (72 blocks, 6 iters)
  gemm_lds<4, 4><<<dim3(12, 6), 256, 0, stream>>>(
      Eb, Eb, Ef, Spb, nullptr, nullptr, nullptr, 120.f, -45.f, 768, 768);
  // 4. WMTb = bf16(lr*Spb@Wb^T + 0.01*WTb); cvec += WMT@bias (288 blocks, 6 iters)
  gemm_lds<4, 3><<<dim3(12, 24), 256, 0, stream>>>(
      Spb, Wb, nullptr, WMTb, WTb, bias, cvec, lr, 0.01f, 768, 3072);
  // 5. out = t @ WMT^T - cvec : grid 128x3 = 384 blocks (TM=64, BN=256, async)
  gemm_big<<<dim3(128, 3), 256, 0, stream>>>(t, WMTb, cvec, out);
}

// Round 5
// 279.481 us; speedup vs baseline: 2.3981x; 1.0068x over previous
//
#include <hip/hip_runtime.h>
#include <stdint.h>

// PCLayer closed form, 5-launch route (r5):
//   conv_w : WTb = bf16(W)^T [768,3072], Wb = bf16(W) [3072,768], cvec = 0
//   E      : Ef(fp32)+Eb(bf16) = lr * WTb @ WTb^T   (one-shot, EPI 5)
//   S''    : Spb = bf16(120*(Eb@Eb^T) - 45*Ef)      (one-shot, EPI 4)
//   WMT    : WMTb = bf16(lr*Spb@Wb^T + 0.01*WTb); cvec += WMT@bias (EPI 3)
//   big    : out = t @ WMT^T - cvec  [8192,768] fp32
// r5 vs r4: gemm_big rebuilt as SINGLE-barrier counted-vmcnt pipeline
// (m201/T3+T4 minimal form). r4's failure mode: two __syncthreads per iter,
// each draining vmcnt(0) -> prefetch dead on arrival, ~2500-3400 cy/iter.
// Now: As AND Bs double-buffered; per iter issue B(k+1) gl2lds -> Bs[nxt],
// cvt+ds_write A(k+1) (reg loads have 1-iter slack), issue A(k+2) reg loads,
// MFMA(k), then ONE asm s_waitcnt vmcnt(4) (B landed, A(k+2) stays in
// flight ACROSS the raw s_barrier) + sched_barrier fences (rule #18).
// BN=128: LDS 48KB -> 3 blocks/CU (launch_bounds(256,3)), grid 768.
// Bank-conflict counters r1/r3/r4 = exactly 4cy/ds_read_b128 (inherent,
// m134) -> no swizzles anywhere.

typedef short bf16x8 __attribute__((ext_vector_type(8)));   // 8 bf16 = 4 VGPRs
typedef float f32x4  __attribute__((ext_vector_type(4)));
typedef unsigned short u16;
typedef unsigned int uint_as1 __attribute__((address_space(1)));
typedef unsigned int uint_as3 __attribute__((address_space(3)));

__device__ __forceinline__ float bf2f(u16 u) {
  union { unsigned int i; float f; } x; x.i = ((unsigned int)u) << 16; return x.f;
}
__device__ __forceinline__ u16 f2bf(float f) {  // round-to-nearest-even
  union { float f; unsigned int i; } x; x.f = f;
  unsigned int r = x.i + 0x7fffu + ((x.i >> 16) & 1u);
  return (u16)(r >> 16);
}
__device__ __forceinline__ void gl2lds16(const void* g, void* l) {
  // async 16B/lane global->LDS; LDS dst = wave-uniform base + lane*16
  __builtin_amdgcn_global_load_lds((uint_as1*)(uintptr_t)g,
                                   (uint_as3*)(uintptr_t)l, 16, 0, 0);
}

// ---- small GEMM: C[M,N] = alpha * A[M,K] @ B[N,K]^T (bf16, lda=ldb=K),
// one-shot over K. Tile 64 x 128, 4 waves 2x2, BK = 32*NK.
// EPI 3: Cb = f2bf(alpha*acc + beta*bf2f(Yb[idx])); cvec[row] += Cb_val*bias[col]
// EPI 4: Cb = f2bf(alpha*acc + beta*Cf[idx])        (Cf read-only fp32)
// EPI 5: Cf = alpha*acc (fp32)  AND  Cb = f2bf(same)
template<int NK, int EPI>
__global__ __launch_bounds__(256, 2)
void gemm_lds(const u16* __restrict__ A, const u16* __restrict__ B,
              float* __restrict__ Cf, u16* __restrict__ Cb,
              const u16* __restrict__ Yb, const float* __restrict__ biasp,
              float* __restrict__ cvec, float alpha, float beta, int K, int ldc)
{
  __shared__ u16 As[64 * 32 * NK];
  __shared__ u16 Bs[128 * 32 * NK];
  const int tid = threadIdx.x, w = tid >> 6, lane = tid & 63;
  const int lm = lane & 15, quad = lane >> 4;
  const int wm = w & 1, wn = w >> 1;
  const int m0 = blockIdx.x * 64, n0 = blockIdx.y * 128;
  const int r = lane >> 2, q = lane & 3;
  const u16* Ag = A + (long)(m0 + w * 16 + r) * K + q * 8;
  const u16* Bg = B + (long)(n0 + w * 32 + r) * K + q * 8;
  u16* Asl = As + w * 16 * 32;   // wave-uniform stage bases
  u16* Bsl = Bs + w * 1024;

  f32x4 acc[2][4] = {};

  for (int kk = 0; kk < K; kk += 32 * NK) {
#pragma unroll
    for (int h = 0; h < NK; ++h) {
      gl2lds16(Ag + kk + h * 32, Asl + h * 2048);
      gl2lds16(Bg + kk + h * 32, Bsl + h * 4096);
      gl2lds16(Bg + 16 * (long)K + kk + h * 32, Bsl + h * 4096 + 512);
    }
    __syncthreads();
#pragma unroll
    for (int h = 0; h < NK; ++h) {
      bf16x8 af[2], bv[4];
#pragma unroll
      for (int i = 0; i < 2; ++i)
        af[i] = *(const bf16x8*)(As + h * 2048 +
                                 (wm * 32 + i * 16 + lm) * 32 + quad * 8);
#pragma unroll
      for (int j = 0; j < 4; ++j)
        bv[j] = *(const bf16x8*)(Bs + h * 4096 +
                                 (wn * 64 + j * 16 + lm) * 32 + quad * 8);
#pragma unroll
      for (int i = 0; i < 2; ++i)
#pragma unroll
        for (int j = 0; j < 4; ++j)
          acc[i][j] = __builtin_amdgcn_mfma_f32_16x16x32_bf16(af[i], bv[j],
                                                              acc[i][j], 0, 0, 0);
    }
    __syncthreads();
  }

  // C/D layout (m89-verified): col = lane&15, row = quad*4 + reg
  const int rbase = m0 + wm * 32 + quad * 4;
  const int cbase = n0 + wn * 64 + lm;
  float bvals[4] = {};
  bool haveb = false;
  if constexpr (EPI == 3) {
#pragma unroll
    for (int j = 0; j < 4; ++j) bvals[j] = biasp[cbase + j * 16];
    haveb = (bvals[0] != 0.f) | (bvals[1] != 0.f) |
            (bvals[2] != 0.f) | (bvals[3] != 0.f);
  }
  float rowsum[2][4] = {};
#pragma unroll
  for (int i = 0; i < 2; ++i)
#pragma unroll
    for (int j = 0; j < 4; ++j) {
      const int col = cbase + j * 16;
#pragma unroll
      for (int rr = 0; rr < 4; ++rr) {
        const long idx = (long)(rbase + i * 16 + rr) * ldc + col;
        const float v = alpha * acc[i][j][rr];
        if constexpr (EPI == 3) {
          const u16 qv = f2bf(v + beta * bf2f(Yb[idx]));
          Cb[idx] = qv;
          rowsum[i][rr] += bf2f(qv) * bvals[j];
        } else if constexpr (EPI == 4) {
          Cb[idx] = f2bf(v + beta * Cf[idx]);
        } else {  // EPI 5
          Cf[idx] = v;
          Cb[idx] = f2bf(v);
        }
      }
    }
  if constexpr (EPI == 3) {
    if (__any(haveb)) {          // bias == 0 here -> whole fold skipped
#pragma unroll
      for (int i = 0; i < 2; ++i)
#pragma unroll
        for (int rr = 0; rr < 4; ++rr) {
          float s = rowsum[i][rr];
          s += __shfl_xor(s, 1); s += __shfl_xor(s, 2);
          s += __shfl_xor(s, 4); s += __shfl_xor(s, 8);
          if (lm == 0) atomicAdd(&cvec[rbase + i * 16 + rr], s);
        }
    }
  }
}

// ---- conv_w: WTb = bf16(W)^T via LDS-tiled transpose (48x12 tiles of 64x64),
// Wb = bf16(W) straight, cvec zeroed by block 0.
__global__ void conv_w(const float* __restrict__ W, u16* __restrict__ WTb,
                       u16* __restrict__ Wb, float* __restrict__ cvec)
{
  __shared__ u16 lds[64 * 72];              // [i_local][o_local], stride 72
  const int bt = blockIdx.x, tid = threadIdx.x;
  if (bt == 0) { cvec[tid] = 0.f; cvec[tid + 256] = 0.f; cvec[tid + 512] = 0.f; }
  const int o0 = (bt / 12) * 64, i0 = (bt % 12) * 64;
  const int ol = tid >> 2, cg4 = tid & 3;   // 64 o-rows, 4 col-groups
#pragma unroll
  for (int p = 0; p < 4; ++p) {             // 16 float4 per o-row
    const float4 v = *(const float4*)(W + (long)(o0 + ol) * 768 + i0 + (cg4 + p * 4) * 4);
    const int ib = (cg4 + p * 4) * 4;
    lds[(ib + 0) * 72 + ol] = f2bf(v.x);
    lds[(ib + 1) * 72 + ol] = f2bf(v.y);
    lds[(ib + 2) * 72 + ol] = f2bf(v.z);
    lds[(ib + 3) * 72 + ol] = f2bf(v.w);
    ushort4 wo;
    wo.x = f2bf(v.x); wo.y = f2bf(v.y); wo.z = f2bf(v.z); wo.w = f2bf(v.w);
    ((ushort4*)(Wb + (long)(o0 + ol) * 768 + i0))[cg4 + p * 4] = wo;
  }
  __syncthreads();
  const int cl = tid >> 2, og = tid & 3;    // 64 i-rows, 4 o-groups of 16
  const u16* src = lds + cl * 72 + og * 16;
  u16* dst = WTb + (long)(i0 + cl) * 3072 + o0 + og * 16;
  ((ushort4*)dst)[0] = ((const ushort4*)src)[0];
  ((ushort4*)dst)[1] = ((const ushort4*)src)[1];
  ((ushort4*)dst)[2] = ((const ushort4*)src)[2];
  ((ushort4*)dst)[3] = ((const ushort4*)src)[3];
}

// ---- big GEMM: out[8192,768] = t @ WMT^T - cvec  (A = fp32 t, cvt in-kernel)
// TM=64 x BN=128, 4 waves 2x2. Single-barrier counted-vmcnt pipeline:
//   iter k: issue B(k+1) gl2lds -> Bs[nxt]; cvt av (=A(k+1)) -> As[nxt]
//   (compiler waits av's own vmcnt(4), leaves B in flight); issue A(k+2)
//   fp32 loads -> av; MFMA(As[cur],Bs[cur]); s_waitcnt vmcnt(4) lgkmcnt(0)
//   [B(k+1) landed, A(k+2) STAYS outstanding across the barrier]; s_barrier.
// A loads get a full iteration of slack (HBM ~900cy hidden); B panel is
// L2-hot (128 x-blocks share it). LDS 48KB -> 3 blocks/CU; grid 128x6=768.
__global__ __launch_bounds__(256, 3)
void gemm_big(const float* __restrict__ T, const u16* __restrict__ B,
              const float* __restrict__ cvec, float* __restrict__ out)
{
  __shared__ u16 As[2][2 * 64 * 32];     // 2 x  8KB [buf][h][row64][k32]
  __shared__ u16 Bs[2][2 * 128 * 32];    // 2 x 16KB [buf][h][row128][k32]
  const int tid = threadIdx.x, w = tid >> 6, lane = tid & 63;
  const int lm = lane & 15, quad = lane >> 4;
  const int wm = w & 1, wn = w >> 1;
  const int m0 = blockIdx.x * 64, n0 = blockIdx.y * 128;
  const int r = lane >> 2, q = lane & 3;
  const u16* Bg = B + (long)(n0 + w * 32 + r) * 3072 + q * 8;
  // A: thread -> rows arow + p*16, float4 chunk kq
  const int arow = tid >> 4, kq = tid & 15;
  const float* Ag = T + (long)(m0 + arow) * 3072 + kq * 4;
  const int h_a = kq >> 3, ks_a = (kq & 7) * 4;

  f32x4 acc[2][4] = {};
  float4 av[4];

  // ---- prologue: A(0)->regs, B(0)->Bs[0]; cvt A(0); load A(1); wait B(0)
#pragma unroll
  for (int p = 0; p < 4; ++p)
    av[p] = *(const float4*)(Ag + (long)(p * 16) * 3072);
#pragma unroll
  for (int h = 0; h < 2; ++h) {
    gl2lds16(Bg + h * 32, Bs[0] + h * 4096 + w * 1024);
    gl2lds16(Bg + 16L * 3072 + h * 32, Bs[0] + h * 4096 + w * 1024 + 512);
  }
#pragma unroll
  for (int p = 0; p < 4; ++p) {
    short4 o;
    o.x = (short)f2bf(av[p].x); o.y = (short)f2bf(av[p].y);
    o.z = (short)f2bf(av[p].z); o.w = (short)f2bf(av[p].w);
    *(short4*)(As[0] + h_a * 2048 + (arow + p * 16) * 32 + ks_a) = o;
  }
#pragma unroll
  for (int p = 0; p < 4; ++p)
    av[p] = *(const float4*)(Ag + (long)(p * 16) * 3072 + 64);
  asm volatile("s_waitcnt vmcnt(4) lgkmcnt(0)" ::: "memory");
  __builtin_amdgcn_sched_barrier(0);
  __builtin_amdgcn_s_barrier();
  __builtin_amdgcn_sched_barrier(0);

  int cur = 0;
  for (int k = 0; k < 48; ++k) {
    const int kk = k * 64;
    const int nxt = cur ^ 1;
    if (k + 1 < 48) {
      // issue B(k+1) -> Bs[nxt] (4 gl2lds/wave; lands under MFMA below)
#pragma unroll
      for (int h = 0; h < 2; ++h) {
        gl2lds16(Bg + kk + 64 + h * 32, Bs[nxt] + h * 4096 + w * 1024);
        gl2lds16(Bg + 16L * 3072 + kk + 64 + h * 32,
                 Bs[nxt] + h * 4096 + w * 1024 + 512);
      }
      // A(k+1): cvt + ds_write into As[nxt] (av had a full iter to land)
#pragma unroll
      for (int p = 0; p < 4; ++p) {
        short4 o;
        o.x = (short)f2bf(av[p].x); o.y = (short)f2bf(av[p].y);
        o.z = (short)f2bf(av[p].z); o.w = (short)f2bf(av[p].w);
        *(short4*)(As[nxt] + h_a * 2048 + (arow + p * 16) * 32 + ks_a) = o;
      }
    }
    if (k + 2 < 48) {
      // issue A(k+2) -> regs; stays in flight across the barrier
#pragma unroll
      for (int p = 0; p < 4; ++p)
        av[p] = *(const float4*)(Ag + (long)(p * 16) * 3072 + kk + 128);
    }
    // MFMA on tiles(k)
    const u16* Asb = As[cur];
    const u16* Bsb = Bs[cur];
#pragma unroll
    for (int h = 0; h < 2; ++h) {
      bf16x8 af[2], bv[4];
#pragma unroll
      for (int i = 0; i < 2; ++i)
        af[i] = *(const bf16x8*)(Asb + h * 2048 +
                                 (wm * 32 + i * 16 + lm) * 32 + quad * 8);
#pragma unroll
      for (int j = 0; j < 4; ++j)
        bv[j] = *(const bf16x8*)(Bsb + h * 4096 +
                                 (wn * 64 + j * 16 + lm) * 32 + quad * 8);
#pragma unroll
      for (int i = 0; i < 2; ++i)
#pragma unroll
        for (int j = 0; j < 4; ++j)
          acc[i][j] = __builtin_amdgcn_mfma_f32_16x16x32_bf16(af[i], bv[j],
                                                              acc[i][j], 0, 0, 0);
    }
    if (k + 1 < 48) {
      if (k + 2 < 48) {
        // outstanding: [B(k+1) x4 oldest, A(k+2) x4 newest] -> wait B only
        asm volatile("s_waitcnt vmcnt(4) lgkmcnt(0)" ::: "memory");
      } else {
        asm volatile("s_waitcnt vmcnt(0) lgkmcnt(0)" ::: "memory");
      }
      __builtin_amdgcn_sched_barrier(0);
      __builtin_amdgcn_s_barrier();
      __builtin_amdgcn_sched_barrier(0);
      cur = nxt;
    }
  }

  // C/D layout (m89-verified): col = lane&15, row = quad*4 + reg
  const int rbase = m0 + wm * 32 + quad * 4;
  const int cbase = n0 + wn * 64 + lm;
  float cj[4];
#pragma unroll
  for (int j = 0; j < 4; ++j) cj[j] = cvec[cbase + j * 16];
#pragma unroll
  for (int i = 0; i < 2; ++i)
#pragma unroll
    for (int j = 0; j < 4; ++j)
#pragma unroll
      for (int rr = 0; rr < 4; ++rr)
        out[(long)(rbase + i * 16 + rr) * 768 + cbase + j * 16] =
            acc[i][j][rr] - cj[j];
}

extern "C" void kernel_launch(void* const* d_in, const int* in_sizes, int n_in,
                              void* d_out, int out_size, void* d_ws, size_t ws_size,
                              hipStream_t stream)
{
  const float* t    = (const float*)d_in[0];   // [8,1024,3072]
  const float* W    = (const float*)d_in[1];   // [3072,768]
  const float* bias = (const float*)d_in[2];   // [3072]
  float* out = (float*)d_out;                  // [8192,768] fp32

  char* p = (char*)d_ws;                       // 18,877,440 B used
  u16*   WTb  = (u16*)(p + 0);                 //  4,718,592  bf16 W^T  [768,3072]
  u16*   Wb   = (u16*)(p + 4718592);           //  4,718,592  bf16 W    [3072,768]
  float* Ef   = (float*)(p + 9437184);         //  2,359,296  E fp32    [768,768]
  u16*   Eb   = (u16*)(p + 11796480);          //  1,179,648  bf16 E
  u16*   Spb  = (u16*)(p + 12976128);          //  1,179,648  bf16 S''
  u16*   WMTb = (u16*)(p + 14155776);          //  4,718,592  bf16 WMT [768,3072]
  float* cvec = (float*)(p + 18874368);        //      3,072  c [768] fp32

  const float lr = 0.001f;

  // 1. WTb + Wb + cvec=0  (576 blocks)
  conv_w<<<576, 256, 0, stream>>>(W, WTb, Wb, cvec);
  // 2. Ef,Eb = lr * WT @ WT^T : one-shot K=3072, BK=128 (72 blocks, 24 iters)
  gemm_lds<4, 5><<<dim3(12, 6), 256, 0, stream>>>(
      WTb, WTb, Ef, Eb, nullptr, nullptr, nullptr, lr, 0.f, 3072, 768);
  // 3. Spb = bf16(120*(Eb@Eb^T) - 45*Ef) : K=768, BK=128 (72 blocks, 6 iters)
  gemm_lds<4, 4><<<dim3(12, 6), 256, 0, stream>>>(
      Eb, Eb, Ef, Spb, nullptr, nullptr, nullptr, 120.f, -45.f, 768, 768);
  // 4. WMTb = bf16(lr*Spb@Wb^T + 0.01*WTb); cvec += WMT@bias (288 blocks, 6 iters)
  gemm_lds<4, 3><<<dim3(12, 24), 256, 0, stream>>>(
      Spb, Wb, nullptr, WMTb, WTb, bias, cvec, lr, 0.01f, 768, 3072);
  // 5. out = t @ WMT^T - cvec : grid 128x6 = 768 blocks, pipelined
  gemm_big<<<dim3(128, 6), 256, 0, stream>>>(t, WMTb, cvec, out);
}

// Round 6
// 274.318 us; speedup vs baseline: 2.4432x; 1.0188x over previous
//
#include <hip/hip_runtime.h>
#include <stdint.h>

// PCLayer closed form, 5-launch route (r6):
//   conv_w : WTb = bf16(W)^T, Wb = bf16(W), cvec = 0   [+ t-conv slice]
//   E      : Ef(fp32)+Eb(bf16) = lr * WTb @ WTb^T      [+ t-conv slice]
//   S''    : Spb = bf16(120*(Eb@Eb^T) - 45*Ef)         [+ t-conv slice]
//   WMT    : WMTb = bf16(lr*Spb@Wb^T + 0.01*WTb); cvec += WMT@bias [+ slice]
//   big    : out = tb @ WMT^T - cvec  [8192,768] fp32  (bf16 A via gl2lds)
// r6 vs r5: pipelining lever abandoned (r4/r5: counted-vmcnt + dbuf = 0 gain;
// kernel is LDS-pipe-dominated and the in-kernel fp32->bf16 A-staging only
// added LDS/VALU work). Instead: (a) t->bf16 conversion HIDDEN inside the
// latency-bound small-chain kernels as extra blocks (24576 conv block-units
// split 4 ways; GEMM blocks first so they schedule first) -> big GEMM reads
// bf16 tb via proven gl2lds path; (b) big GEMM = r1's 66.5us structure with
// NK=4 (BK=128): barrier count 48->24, LDS 48KB keeps 3 blocks/CU (grid 768).

typedef short bf16x8 __attribute__((ext_vector_type(8)));   // 8 bf16 = 4 VGPRs
typedef float f32x4  __attribute__((ext_vector_type(4)));
typedef unsigned short u16;
typedef unsigned int uint_as1 __attribute__((address_space(1)));
typedef unsigned int uint_as3 __attribute__((address_space(3)));

__device__ __forceinline__ float bf2f(u16 u) {
  union { unsigned int i; float f; } x; x.i = ((unsigned int)u) << 16; return x.f;
}
__device__ __forceinline__ u16 f2bf(float f) {  // round-to-nearest-even
  union { float f; unsigned int i; } x; x.f = f;
  unsigned int r = x.i + 0x7fffu + ((x.i >> 16) & 1u);
  return (u16)(r >> 16);
}
__device__ __forceinline__ void gl2lds16(const void* g, void* l) {
  // async 16B/lane global->LDS; LDS dst = wave-uniform base + lane*16
  __builtin_amdgcn_global_load_lds((uint_as1*)(uintptr_t)g,
                                   (uint_as3*)(uintptr_t)l, 16, 0, 0);
}

// one 256-thread block-unit of t -> tb conversion (float4 per thread)
__device__ __forceinline__ void conv_slice(const float* __restrict__ t,
                                           const float* __restrict__ bias,
                                           u16* __restrict__ tb,
                                           int blockUnit, int tid)
{
  const long i4 = (long)blockUnit * 256 + tid;
  const float4 v = ((const float4*)t)[i4];
  const float4 bb = ((const float4*)bias)[(int)(i4 % 768)];
  ushort4 o;
  o.x = f2bf(v.x - bb.x); o.y = f2bf(v.y - bb.y);
  o.z = f2bf(v.z - bb.z); o.w = f2bf(v.w - bb.w);
  ((ushort4*)tb)[i4] = o;
}

// ---- GEMM: C[M,N] = alpha * A[M,K] @ B[N,K]^T (bf16, lda=ldb=K), one-shot
// over K. Tile 64 x 128, 4 waves 2x2, BK = 32*NK. 2-barrier loop (proven).
// Blocks >= gemmBlocks perform a t->tb conversion block-unit instead.
// EPI 3: Cb = f2bf(alpha*acc + beta*bf2f(Yb[idx])); cvec[row] += Cb*bias[col]
// EPI 4: Cb = f2bf(alpha*acc + beta*Cf[idx])        (Cf read-only fp32)
// EPI 5: Cf = alpha*acc (fp32)  AND  Cb = f2bf(same)
// EPI 6: Cf[idx] = alpha*acc - cvec[col]            (big-GEMM output)
template<int NK, int EPI>
__global__ __launch_bounds__(256, 2)
void gemm_lds(const u16* __restrict__ A, const u16* __restrict__ B,
              float* __restrict__ Cf, u16* __restrict__ Cb,
              const u16* __restrict__ Yb, const float* __restrict__ biasp,
              float* __restrict__ cvec, float alpha, float beta,
              int K, int ldc, int nbx, int gemmBlocks, int convBase,
              const float* __restrict__ tsrc, const float* __restrict__ tbias,
              u16* __restrict__ tbdst)
{
  __shared__ u16 As[64 * 32 * NK];
  __shared__ u16 Bs[128 * 32 * NK];
  const int tid = threadIdx.x;
  if ((int)blockIdx.x >= gemmBlocks) {   // hidden t->tb conversion block
    conv_slice(tsrc, tbias, tbdst, (int)blockIdx.x - gemmBlocks + convBase, tid);
    return;
  }
  const int bx = (int)blockIdx.x % nbx, by = (int)blockIdx.x / nbx;
  const int w = tid >> 6, lane = tid & 63;
  const int lm = lane & 15, quad = lane >> 4;
  const int wm = w & 1, wn = w >> 1;
  const int m0 = bx * 64, n0 = by * 128;
  const int r = lane >> 2, q = lane & 3;
  const u16* Ag = A + (long)(m0 + w * 16 + r) * K + q * 8;
  const u16* Bg = B + (long)(n0 + w * 32 + r) * K + q * 8;
  u16* Asl = As + w * 16 * 32;   // wave-uniform stage bases
  u16* Bsl = Bs + w * 1024;

  f32x4 acc[2][4] = {};

  for (int kk = 0; kk < K; kk += 32 * NK) {
#pragma unroll
    for (int h = 0; h < NK; ++h) {
      gl2lds16(Ag + kk + h * 32, Asl + h * 2048);
      gl2lds16(Bg + kk + h * 32, Bsl + h * 4096);
      gl2lds16(Bg + 16 * (long)K + kk + h * 32, Bsl + h * 4096 + 512);
    }
    __syncthreads();
#pragma unroll
    for (int h = 0; h < NK; ++h) {
      bf16x8 af[2], bv[4];
#pragma unroll
      for (int i = 0; i < 2; ++i)
        af[i] = *(const bf16x8*)(As + h * 2048 +
                                 (wm * 32 + i * 16 + lm) * 32 + quad * 8);
#pragma unroll
      for (int j = 0; j < 4; ++j)
        bv[j] = *(const bf16x8*)(Bs + h * 4096 +
                                 (wn * 64 + j * 16 + lm) * 32 + quad * 8);
#pragma unroll
      for (int i = 0; i < 2; ++i)
#pragma unroll
        for (int j = 0; j < 4; ++j)
          acc[i][j] = __builtin_amdgcn_mfma_f32_16x16x32_bf16(af[i], bv[j],
                                                              acc[i][j], 0, 0, 0);
    }
    __syncthreads();
  }

  // C/D layout (m89-verified): col = lane&15, row = quad*4 + reg
  const int rbase = m0 + wm * 32 + quad * 4;
  const int cbase = n0 + wn * 64 + lm;
  float bvals[4] = {};
  bool haveb = false;
  if constexpr (EPI == 3) {
#pragma unroll
    for (int j = 0; j < 4; ++j) bvals[j] = biasp[cbase + j * 16];
    haveb = (bvals[0] != 0.f) | (bvals[1] != 0.f) |
            (bvals[2] != 0.f) | (bvals[3] != 0.f);
  }
  float cj[4];
  if constexpr (EPI == 6) {
#pragma unroll
    for (int j = 0; j < 4; ++j) cj[j] = cvec[cbase + j * 16];
  }
  float rowsum[2][4] = {};
#pragma unroll
  for (int i = 0; i < 2; ++i)
#pragma unroll
    for (int j = 0; j < 4; ++j) {
      const int col = cbase + j * 16;
#pragma unroll
      for (int rr = 0; rr < 4; ++rr) {
        const long idx = (long)(rbase + i * 16 + rr) * ldc + col;
        const float v = alpha * acc[i][j][rr];
        if constexpr (EPI == 3) {
          const u16 qv = f2bf(v + beta * bf2f(Yb[idx]));
          Cb[idx] = qv;
          rowsum[i][rr] += bf2f(qv) * bvals[j];
        } else if constexpr (EPI == 4) {
          Cb[idx] = f2bf(v + beta * Cf[idx]);
        } else if constexpr (EPI == 5) {
          Cf[idx] = v;
          Cb[idx] = f2bf(v);
        } else {  // EPI 6
          Cf[idx] = v - cj[j];
        }
      }
    }
  if constexpr (EPI == 3) {
    if (__any(haveb)) {          // bias == 0 here -> whole fold skipped
#pragma unroll
      for (int i = 0; i < 2; ++i)
#pragma unroll
        for (int rr = 0; rr < 4; ++rr) {
          float s = rowsum[i][rr];
          s += __shfl_xor(s, 1); s += __shfl_xor(s, 2);
          s += __shfl_xor(s, 4); s += __shfl_xor(s, 8);
          if (lm == 0) atomicAdd(&cvec[rbase + i * 16 + rr], s);
        }
    }
  }
}

// ---- conv_w: WTb = bf16(W)^T via LDS-tiled transpose (48x12 tiles of 64x64),
// Wb = bf16(W) straight, cvec zeroed by block 0; blocks >= 576 convert t.
__global__ void conv_w(const float* __restrict__ W, const float* __restrict__ t,
                       const float* __restrict__ bias, u16* __restrict__ WTb,
                       u16* __restrict__ Wb, u16* __restrict__ tb,
                       float* __restrict__ cvec)
{
  __shared__ u16 lds[64 * 72];              // [i_local][o_local], stride 72
  const int bt = blockIdx.x, tid = threadIdx.x;
  if (bt >= 576) { conv_slice(t, bias, tb, bt - 576, tid); return; }
  if (bt == 0) { cvec[tid] = 0.f; cvec[tid + 256] = 0.f; cvec[tid + 512] = 0.f; }
  const int o0 = (bt / 12) * 64, i0 = (bt % 12) * 64;
  const int ol = tid >> 2, cg4 = tid & 3;   // 64 o-rows, 4 col-groups
#pragma unroll
  for (int p = 0; p < 4; ++p) {             // 16 float4 per o-row
    const float4 v = *(const float4*)(W + (long)(o0 + ol) * 768 + i0 + (cg4 + p * 4) * 4);
    const int ib = (cg4 + p * 4) * 4;
    lds[(ib + 0) * 72 + ol] = f2bf(v.x);
    lds[(ib + 1) * 72 + ol] = f2bf(v.y);
    lds[(ib + 2) * 72 + ol] = f2bf(v.z);
    lds[(ib + 3) * 72 + ol] = f2bf(v.w);
    ushort4 wo;
    wo.x = f2bf(v.x); wo.y = f2bf(v.y); wo.z = f2bf(v.z); wo.w = f2bf(v.w);
    ((ushort4*)(Wb + (long)(o0 + ol) * 768 + i0))[cg4 + p * 4] = wo;
  }
  __syncthreads();
  const int cl = tid >> 2, og = tid & 3;    // 64 i-rows, 4 o-groups of 16
  const u16* src = lds + cl * 72 + og * 16;
  u16* dst = WTb + (long)(i0 + cl) * 3072 + o0 + og * 16;
  ((ushort4*)dst)[0] = ((const ushort4*)src)[0];
  ((ushort4*)dst)[1] = ((const ushort4*)src)[1];
  ((ushort4*)dst)[2] = ((const ushort4*)src)[2];
  ((ushort4*)dst)[3] = ((const ushort4*)src)[3];
}

extern "C" void kernel_launch(void* const* d_in, const int* in_sizes, int n_in,
                              void* d_out, int out_size, void* d_ws, size_t ws_size,
                              hipStream_t stream)
{
  const float* t    = (const float*)d_in[0];   // [8,1024,3072]
  const float* W    = (const float*)d_in[1];   // [3072,768]
  const float* bias = (const float*)d_in[2];   // [3072]
  float* out = (float*)d_out;                  // [8192,768] fp32

  char* p = (char*)d_ws;                       // 69,209,088 B used
  u16*   tb   = (u16*)(p + 0);                 // 50,331,648  bf16 t-b  [8192,3072]
  u16*   WTb  = (u16*)(p + 50331648);          //  4,718,592  bf16 W^T  [768,3072]
  u16*   Wb   = (u16*)(p + 55050240);          //  4,718,592  bf16 W    [3072,768]
  float* Ef   = (float*)(p + 59768832);        //  2,359,296  E fp32    [768,768]
  u16*   Eb   = (u16*)(p + 62128128);          //  1,179,648  bf16 E
  u16*   Spb  = (u16*)(p + 63307776);          //  1,179,648  bf16 S''
  u16*   WMTb = (u16*)(p + 64487424);          //  4,718,592  bf16 WMT [768,3072]
  float* cvec = (float*)(p + 69206016);        //      3,072  c [768] fp32

  const float lr = 0.001f;
  // t->tb conversion: 24576 block-units, split across the 4 small kernels
  // (GEMM/transpose blocks first so they schedule first; conv blocks fill
  // the idle CUs/BW while the latency-bound chains run).

  // 1. WTb + Wb + cvec=0  (576 tile blocks + conv units [0,6144))
  conv_w<<<576 + 6144, 256, 0, stream>>>(W, t, bias, WTb, Wb, tb, cvec);
  // 2. Ef,Eb = lr * WT @ WT^T : K=3072, BK=128 (72 gemm blocks + conv [6144,12288))
  gemm_lds<4, 5><<<72 + 6144, 256, 0, stream>>>(
      WTb, WTb, Ef, Eb, nullptr, nullptr, nullptr, lr, 0.f, 3072, 768,
      12, 72, 6144, t, bias, tb);
  // 3. Spb = bf16(120*(Eb@Eb^T) - 45*Ef) : K=768 (72 + conv [12288,18432))
  gemm_lds<4, 4><<<72 + 6144, 256, 0, stream>>>(
      Eb, Eb, Ef, Spb, nullptr, nullptr, nullptr, 120.f, -45.f, 768, 768,
      12, 72, 12288, t, bias, tb);
  // 4. WMTb = bf16(lr*Spb@Wb^T + 0.01*WTb); cvec += WMT@bias (288 + conv [18432,24576))
  gemm_lds<4, 3><<<288 + 6144, 256, 0, stream>>>(
      Spb, Wb, nullptr, WMTb, WTb, bias, cvec, lr, 0.01f, 768, 3072,
      12, 288, 18432, t, bias, tb);
  // 5. out = tb @ WMT^T - cvec : grid 128x6 = 768 blocks, BK=128 (24 iters),
  //    LDS 48KB -> 3 blocks/CU, bf16 A via gl2lds (r1-proven structure)
  gemm_lds<4, 6><<<768, 256, 0, stream>>>(
      tb, WMTb, out, nullptr, nullptr, nullptr, cvec, 1.f, 0.f, 3072, 768,
      128, 768, 0, nullptr, nullptr, nullptr);
}